// Round 8
// baseline (275.905 us; speedup 1.0000x reference)
//
#include <hip/hip_runtime.h>

// FromRGB fully fused:
//   x[8,16,512,512] --(IHT up2 + blur down2 + Haar down2 == one separable
//   4x4 stride-2 stencil)--> new_in[8,16,256,256]  (output 0, kept in regs)
//   --(1x1 conv 16->512 * 0.25, +bias, leakyrelu(0.2)*sqrt2)--> out[8,512,256,256]
//
// Composed 1D filters (x16), [analysis][synthesis]:
//   (l,l): [1, 7, 7, 1]   (l,h): [1, 1,-1,-1]
//   (h,l): [1, 5,-5,-1]   (h,h): [1,-1,-1, 1]
//
// R8 changes vs R7 (write-geometry attack; occupancy held at 8 waves/CU):
//  * 512-thread blocks covering 8 rows x 256 cols -> each (block, o-plane)
//    visit stores 8 KB contiguous (2x R7's 4 KB) before the 256 KB plane hop.
//  * grid = 256 blocks = exactly 1 block/CU (same 2 waves/SIMD as R7).
//  * per-block o-rotation decorrelates which plane all blocks write at a
//    given instant (spreads DRAM bank/page pressure).
//  * unchanged: scalar-broadcast weights from d_ws (R7), shfl edge cols, nt.

#define H_IN 512
#define W_IN 512
#define H_OUT 256
#define W_OUT 256
#define NB 8
#define C_MID 16
#define C_OUT 512

typedef float fx4 __attribute__((ext_vector_type(4)));

__device__ __forceinline__ float cL(int fsel, float a0, float a1, float a2, float a3) {
  return fsel == 0 ? (a0 + 7.f*a1 + 7.f*a2 + a3) : (a0 + a1 - a2 - a3);
}
__device__ __forceinline__ float cH(int fsel, float a0, float a1, float a2, float a3) {
  return fsel == 0 ? (a0 + 5.f*a1 - 5.f*a2 - a3) : (a0 - a1 - a2 + a3);
}

__device__ __forceinline__ fx4 vfma(fx4 v, float s, fx4 a) {
  a.x = fmaf(v.x, s, a.x); a.y = fmaf(v.y, s, a.y);
  a.z = fmaf(v.z, s, a.z); a.w = fmaf(v.w, s, a.w);
  return a;
}

// Prep: pack scaled weights+bias into d_ws, 32-float (128 B) stride per o:
//   wpk[o*32 + c]  = w[o][c] * sqrt2*0.25/256   (c = 0..15)
//   wpk[o*32 + 16] = bias[o] * sqrt2
__global__ __launch_bounds__(256) void k_prep(const float* __restrict__ w,
                                              const float* __restrict__ bias,
                                              float* __restrict__ wpk) {
  const int o = blockIdx.x * 256 + threadIdx.x;   // 0..511
  const float s2 = 1.41421356237309515f;
  const float wscale = s2 * 0.25f * (1.f / 256.f);
#pragma unroll
  for (int c = 0; c < 16; ++c) wpk[o * 32 + c] = w[o * 16 + c] * wscale;
  wpk[o * 32 + 16] = bias[o] * s2;
}

__global__ __launch_bounds__(512) void k_fused(const float* __restrict__ x,
                                               const float* __restrict__ wpk,
                                               float* __restrict__ nin,
                                               float* __restrict__ out) {
  const int t = threadIdx.x;                  // 0..511
  const int q = t & 63;                       // output cols 4q..4q+3
  const int y = blockIdx.x * 8 + (t >> 6);    // output row (wave-uniform)
  const int b = blockIdx.y;                   // image
  const int y0 = 2 * y - 1;

  const float WL[2][4] = {{1.f, 7.f, 7.f, 1.f}, {1.f, 1.f, -1.f, -1.f}};
  const float WH[2][4] = {{1.f, 5.f, -5.f, -1.f}, {1.f, -1.f, -1.f, 1.f}};

  // ---- Phase 1: stencil. acc[comp*4+ch] = nin*256 for this thread's quad ----
  fx4 acc[16];
#pragma unroll
  for (int c = 0; c < 16; ++c) acc[c] = (fx4){0.f, 0.f, 0.f, 0.f};

#pragma unroll
  for (int ch = 0; ch < 4; ++ch) {
#pragma unroll
    for (int g = 0; g < 4; ++g) {
      const int gY = g & 1, gX = g >> 1;
      const float sg = (g == 1 || g == 2) ? -1.f : 1.f;
      const float* xp = x + (size_t)(b * 16 + g * 4 + ch) * (H_IN * W_IN);
#pragma unroll
      for (int p = 0; p < 4; ++p) {
        const int yy = y0 + p;
        if (yy < 0 || yy >= H_IN) continue;   // wave-uniform branch
        const float* row = xp + (size_t)yy * W_IN + 8 * q;
        const fx4 m0 = *reinterpret_cast<const fx4*>(row);
        const fx4 m1 = *reinterpret_cast<const fx4*>(row + 4);
        // Edge cols via neighbor lanes (wave spans the full row).
        const float c0s = __shfl(m1.w, q - 1);
        const float c9s = __shfl(m0.x, q + 1);
        const float cc0 = (q > 0) ? c0s : 0.f;
        const float cc9 = (q < 63) ? c9s : 0.f;
        const float cc[10] = {cc0, m0.x, m0.y, m0.z, m0.w,
                              m1.x, m1.y, m1.z, m1.w, cc9};
        const float wl = sg * WL[gY][p];
        const float wh = sg * WH[gY][p];
        fx4 vL, vH;
        vL.x = cL(gX, cc[0], cc[1], cc[2], cc[3]);
        vL.y = cL(gX, cc[2], cc[3], cc[4], cc[5]);
        vL.z = cL(gX, cc[4], cc[5], cc[6], cc[7]);
        vL.w = cL(gX, cc[6], cc[7], cc[8], cc[9]);
        vH.x = cH(gX, cc[0], cc[1], cc[2], cc[3]);
        vH.y = cH(gX, cc[2], cc[3], cc[4], cc[5]);
        vH.z = cH(gX, cc[4], cc[5], cc[6], cc[7]);
        vH.w = cH(gX, cc[6], cc[7], cc[8], cc[9]);
        acc[0 * 4 + ch] = vfma(vL, wl, acc[0 * 4 + ch]);
        acc[1 * 4 + ch] = vfma(vL, wh, acc[1 * 4 + ch]);
        acc[2 * 4 + ch] = vfma(vH, wl, acc[2 * 4 + ch]);
        acc[3 * 4 + ch] = vfma(vH, wh, acc[3 * 4 + ch]);
      }
    }
  }

  // nin (output 0), scaled 1/256, nontemporal (never re-read).
  const float inv = 1.f / 256.f;
#pragma unroll
  for (int c = 0; c < 16; ++c) {
    fx4 r;
    r.x = acc[c].x * inv; r.y = acc[c].y * inv;
    r.z = acc[c].z * inv; r.w = acc[c].w * inv;
    __builtin_nontemporal_store(r, reinterpret_cast<fx4*>(
        nin + ((size_t)(b * C_MID + c) * H_OUT + y) * W_OUT + 4 * q));
  }

  // ---- Phase 2: 1x1 conv; weights via wave-uniform scalar loads.
  // o-walk rotated per block so concurrent blocks hit different planes.
  float* op = out + ((size_t)(b * C_OUT) * H_OUT + y) * W_OUT + 4 * q;
  const int orot = (blockIdx.x * 5) & (C_OUT - 1);
#pragma unroll 2
  for (int oi = 0; oi < C_OUT; ++oi) {
    const int o = (oi + orot) & (C_OUT - 1);
    const float* __restrict__ wrow = wpk + (o << 5);
    const float bo = wrow[16];
    fx4 a; a.x = bo; a.y = bo; a.z = bo; a.w = bo;
#pragma unroll
    for (int c = 0; c < 16; ++c) a = vfma(acc[c], wrow[c], a);
    // sqrt2 folded into weights/bias: out = max(u, 0.2u)
    a.x = fmaxf(a.x, 0.2f * a.x);
    a.y = fmaxf(a.y, 0.2f * a.y);
    a.z = fmaxf(a.z, 0.2f * a.z);
    a.w = fmaxf(a.w, 0.2f * a.w);
    __builtin_nontemporal_store(a,
        reinterpret_cast<fx4*>(op + (size_t)o * (H_OUT * W_OUT)));
  }
}

extern "C" void kernel_launch(void* const* d_in, const int* in_sizes, int n_in,
                              void* d_out, int out_size, void* d_ws, size_t ws_size,
                              hipStream_t stream) {
  const float* x    = (const float*)d_in[0];
  const float* w    = (const float*)d_in[1];
  const float* bias = (const float*)d_in[2];
  float* nin = (float*)d_out;                                       // output 0
  float* out = (float*)d_out + (size_t)NB * C_MID * H_OUT * W_OUT;  // output 1
  float* wpk = (float*)d_ws;  // 512*32*4 B = 64 KB packed weight table

  k_prep<<<dim3(2), dim3(256), 0, stream>>>(w, bias, wpk);
  k_fused<<<dim3(32, 8), dim3(512), 0, stream>>>(x, wpk, nin, out);
}